// Round 1
// baseline (451.784 us; speedup 1.0000x reference)
//
#include <hip/hip_runtime.h>
#include <math.h>

// Problem constants (fixed by the reference file)
#define B_    4
#define LQ_   4096
#define C_    384
#define NH_   6
#define NP_   4
#define HL_   64
#define WL_   64
#define LV_   (HL_ * WL_)          // 4096
#define ROWS_ (B_ * LQ_)           // 16384 (query rows; feat rows coincide: B*LV = 16384)
#define EPS_  1e-6f
#define NOFF_ 48                   // NH*NL*NP*2
#define NLOG_ 24                   // NH*NL*NP

// ---------------------------------------------------------------------------
// LayerNorm: one wave (64 lanes) per row, 6 elements per lane.
// Handles both query rows (0..16383) and feat rows (16384..32767).
// ---------------------------------------------------------------------------
__global__ __launch_bounds__(256) void ln_kernel(
    const float* __restrict__ query, const float* __restrict__ feat,
    const float* __restrict__ qg, const float* __restrict__ qb,
    const float* __restrict__ fg, const float* __restrict__ fb,
    float* __restrict__ qout, float* __restrict__ fout)
{
    int wid  = threadIdx.x >> 6;
    int lane = threadIdx.x & 63;
    int row  = blockIdx.x * 4 + wid;          // 0 .. 32767
    const float *src, *g, *bsh;
    float* dst;
    int r;
    if (row < ROWS_) { src = query; g = qg; bsh = qb; dst = qout; r = row; }
    else             { src = feat;  g = fg; bsh = fb; dst = fout; r = row - ROWS_; }

    const float* x = src + (size_t)r * C_;
    float v[6];
    float s = 0.f;
#pragma unroll
    for (int k = 0; k < 6; ++k) { v[k] = x[lane + 64 * k]; s += v[k]; }
#pragma unroll
    for (int off = 32; off; off >>= 1) s += __shfl_xor(s, off);
    float mu = s * (1.f / C_);

    float s2 = 0.f;
#pragma unroll
    for (int k = 0; k < 6; ++k) { float d = v[k] - mu; s2 += d * d; }
#pragma unroll
    for (int off = 32; off; off >>= 1) s2 += __shfl_xor(s2, off);
    float rs = rsqrtf(s2 * (1.f / C_) + EPS_);

    float* y = dst + (size_t)r * C_;
#pragma unroll
    for (int k = 0; k < 6; ++k) {
        int c = lane + 64 * k;
        y[c] = (v[k] - mu) * rs * g[c] + bsh[c];
    }
}

// ---------------------------------------------------------------------------
// FP32 tiled GEMM: C[M,N] = A[M,K] @ W[K,N] + bias, optional fused residual:
//   out = resid + gamma * (A@W + bias)
// 64x64 tile per block, 256 threads, 4x4 outputs/thread, BK=16.
// Requires M%64==0, N%64==0, K%16==0 (holds: 16384, 384, 384).
// ---------------------------------------------------------------------------
__global__ __launch_bounds__(256) void gemm64(
    const float* __restrict__ A, const float* __restrict__ W,
    const float* __restrict__ bias,
    const float* __restrict__ resid, const float* __restrict__ gamma,
    float* __restrict__ C, int M, int N, int K)
{
    __shared__ float As[64][17];
    __shared__ float Bs[16][64];

    int tid = threadIdx.x;
    int tx = tid & 15, ty = tid >> 4;
    int m0 = blockIdx.y * 64, n0 = blockIdx.x * 64;

    int ar = tid >> 2, ac = (tid & 3) << 2;   // A-tile loader: 64 rows x 16 cols
    int br = tid >> 4, bc = (tid & 15) << 2;  // B-tile loader: 16 rows x 64 cols

    float acc[4][4] = {};

    for (int k0 = 0; k0 < K; k0 += 16) {
        float4 a4 = *(const float4*)(A + (size_t)(m0 + ar) * K + k0 + ac);
        As[ar][ac + 0] = a4.x; As[ar][ac + 1] = a4.y;
        As[ar][ac + 2] = a4.z; As[ar][ac + 3] = a4.w;
        float4 b4 = *(const float4*)(W + (size_t)(k0 + br) * N + n0 + bc);
        Bs[br][bc + 0] = b4.x; Bs[br][bc + 1] = b4.y;
        Bs[br][bc + 2] = b4.z; Bs[br][bc + 3] = b4.w;
        __syncthreads();

#pragma unroll
        for (int kk = 0; kk < 16; ++kk) {
            float a[4], bb[4];
#pragma unroll
            for (int i = 0; i < 4; ++i) a[i] = As[ty * 4 + i][kk];
#pragma unroll
            for (int j = 0; j < 4; ++j) bb[j] = Bs[kk][tx * 4 + j];
#pragma unroll
            for (int i = 0; i < 4; ++i)
#pragma unroll
                for (int j = 0; j < 4; ++j) acc[i][j] += a[i] * bb[j];
        }
        __syncthreads();
    }

#pragma unroll
    for (int i = 0; i < 4; ++i) {
#pragma unroll
        for (int j = 0; j < 4; ++j) {
            int row = m0 + ty * 4 + i, col = n0 + tx * 4 + j;
            float vv = acc[i][j] + bias[col];
            size_t o = (size_t)row * N + col;
            if (resid) C[o] = resid[o] + gamma[col] * vv;
            else       C[o] = vv;
        }
    }
}

// ---------------------------------------------------------------------------
// Small GEMM (N = 48 or 24): one block (64 threads) per row of A.
// A row staged in LDS; lane n computes the dot with column n of W.
// ---------------------------------------------------------------------------
__global__ __launch_bounds__(64) void small_gemm(
    const float* __restrict__ A, const float* __restrict__ W,
    const float* __restrict__ bias, float* __restrict__ C, int N, int K)
{
    __shared__ float arow[C_];
    int row = blockIdx.x;
    int t = threadIdx.x;
    for (int i = t; i < K; i += 64) arow[i] = A[(size_t)row * K + i];
    __syncthreads();
    if (t < N) {
        float s = bias[t];
        for (int k = 0; k < K; ++k) s += arow[k] * W[(size_t)k * N + t];
        C[(size_t)row * N + t] = s;
    }
}

// ---------------------------------------------------------------------------
// Fused softmax(4) + bilinear sampling. One block per (b,q), 384 threads.
// Threads t<24 compute per-(h,p) softmax weight, sample location, 4 corner
// indices + folded weights into LDS. Then thread (h,d)=t reads 16 gathers.
// ---------------------------------------------------------------------------
__global__ __launch_bounds__(384) void sample_kernel(
    const float* __restrict__ value,   // [B*LV, C]
    const float* __restrict__ rp,      // [B*LQ, 2]  (NL=1)
    const float* __restrict__ offs,    // [B*LQ, 48]
    const float* __restrict__ logits,  // [B*LQ, 24]
    float* __restrict__ attn)          // [B*LQ, C]
{
    __shared__ float w_s[NH_][NP_][4];
    __shared__ int   pos_s[NH_][NP_][4];

    int bq = blockIdx.x;
    int b  = bq / LQ_;
    int t  = threadIdx.x;

    if (t < NLOG_) {
        int h = t >> 2, p = t & 3;
        // softmax over the 4 points of head h (redundant per p, but cheap)
        const float* lg = logits + (size_t)bq * NLOG_ + h * 4;
        float l0 = lg[0], l1 = lg[1], l2 = lg[2], l3 = lg[3];
        float mx = fmaxf(fmaxf(l0, l1), fmaxf(l2, l3));
        float e0 = expf(l0 - mx), e1 = expf(l1 - mx), e2 = expf(l2 - mx), e3 = expf(l3 - mx);
        float den = e0 + e1 + e2 + e3;
        float ep = (p == 0) ? e0 : (p == 1) ? e1 : (p == 2) ? e2 : e3;
        float aw = ep / den;

        float rx = rp[(size_t)bq * 2 + 0];
        float ry = rp[(size_t)bq * 2 + 1];
        float ox = offs[(size_t)bq * NOFF_ + t * 2 + 0];
        float oy = offs[(size_t)bq * NOFF_ + t * 2 + 1];
        float lx = rx + ox * (1.0f / WL_);
        float ly = ry + oy * (1.0f / HL_);
        float x = lx * (float)WL_ - 0.5f;
        float y = ly * (float)HL_ - 0.5f;
        float x0f = floorf(x), y0f = floorf(y);
        float wx = x - x0f, wy = y - y0f;
        int x0 = (int)x0f, y0 = (int)y0f;
#pragma unroll
        for (int c = 0; c < 4; ++c) {
            int xi = x0 + (c & 1);
            int yi = y0 + (c >> 1);
            bool valid = (xi >= 0) && (xi < WL_) && (yi >= 0) && (yi < HL_);
            int xc = xi < 0 ? 0 : (xi > WL_ - 1 ? WL_ - 1 : xi);
            int yc = yi < 0 ? 0 : (yi > HL_ - 1 ? HL_ - 1 : yi);
            float wc = ((c & 1) ? wx : 1.f - wx) * ((c >> 1) ? wy : 1.f - wy);
            pos_s[h][p][c] = yc * WL_ + xc;
            w_s[h][p][c]   = valid ? wc * aw : 0.f;
        }
    }
    __syncthreads();

    int h = t >> 6, d = t & 63;
    const float* vb = value + ((size_t)b * LV_) * C_ + h * 64 + d;
    float acc = 0.f;
#pragma unroll
    for (int p = 0; p < NP_; ++p) {
#pragma unroll
        for (int c = 0; c < 4; ++c) {
            acc += w_s[h][p][c] * vb[(size_t)pos_s[h][p][c] * C_];
        }
    }
    attn[(size_t)bq * C_ + t] = acc;
}

// ---------------------------------------------------------------------------
extern "C" void kernel_launch(void* const* d_in, const int* in_sizes, int n_in,
                              void* d_out, int out_size, void* d_ws, size_t ws_size,
                              hipStream_t stream)
{
    const float* query  = (const float*)d_in[0];
    const float* rp     = (const float*)d_in[1];
    const float* feat   = (const float*)d_in[2];
    // d_in[3] spatial_shapes, d_in[4] level_start_index: compile-time constants
    const float* ln_q_g = (const float*)d_in[5];
    const float* ln_q_b = (const float*)d_in[6];
    const float* ln_f_g = (const float*)d_in[7];
    const float* ln_f_b = (const float*)d_in[8];
    const float* gamma  = (const float*)d_in[9];
    const float* Wv     = (const float*)d_in[10];
    const float* bv     = (const float*)d_in[11];
    const float* Wo     = (const float*)d_in[12];
    const float* bo     = (const float*)d_in[13];
    const float* Wa     = (const float*)d_in[14];
    const float* ba     = (const float*)d_in[15];
    const float* Wout   = (const float*)d_in[16];
    const float* bout   = (const float*)d_in[17];
    float* out = (float*)d_out;

    // Workspace layout (floats): q | fbuf (reused as attn) | value | offs | logits
    float* ws     = (float*)d_ws;
    float* q      = ws;                                  // 16384*384
    float* fbuf   = q      + (size_t)ROWS_ * C_;         // 16384*384
    float* value  = fbuf   + (size_t)ROWS_ * C_;         // 16384*384
    float* offs   = value  + (size_t)ROWS_ * C_;         // 16384*48
    float* logits = offs   + (size_t)ROWS_ * NOFF_;      // 16384*24
    // total = 20,054,016 floats = 80.2 MB

    // 1) LayerNorm both query and feat (32768 rows, 4 rows/block)
    ln_kernel<<<8192, 256, 0, stream>>>(query, feat, ln_q_g, ln_q_b,
                                        ln_f_g, ln_f_b, q, fbuf);

    // 2) value = f @ Wv + bv      [16384,384]x[384,384]
    gemm64<<<dim3(C_ / 64, ROWS_ / 64), 256, 0, stream>>>(
        fbuf, Wv, bv, nullptr, nullptr, value, ROWS_, C_, C_);

    // 3) offsets = q @ Wo + bo    [16384,384]x[384,48]
    small_gemm<<<ROWS_, 64, 0, stream>>>(q, Wo, bo, offs, NOFF_, C_);

    // 4) logits = q @ Wa + ba     [16384,384]x[384,24]
    small_gemm<<<ROWS_, 64, 0, stream>>>(q, Wa, ba, logits, NLOG_, C_);

    // 5) fused softmax + bilinear sampling -> attn (reuses fbuf)
    float* attn = fbuf;
    sample_kernel<<<ROWS_, 384, 0, stream>>>(value, rp, offs, logits, attn);

    // 6) out = query + gamma * (attn @ Wout + bout)
    gemm64<<<dim3(C_ / 64, ROWS_ / 64), 256, 0, stream>>>(
        attn, Wout, bout, query, gamma, out, ROWS_, C_, C_);
}

// Round 2
// 202.657 us; speedup vs baseline: 2.2293x; 2.2293x over previous
//
#include <hip/hip_runtime.h>
#include <math.h>

// Problem constants (fixed by the reference file)
#define B_    4
#define LQ_   4096
#define C_    384
#define NH_   6
#define NP_   4
#define HL_   64
#define WL_   64
#define LV_   (HL_ * WL_)          // 4096
#define ROWS_ (B_ * LQ_)           // 16384
#define EPS_  1e-6f
#define NOFF_ 48                   // NH*NL*NP*2
#define NLOG_ 24                   // NH*NL*NP

typedef unsigned short u16;
typedef __bf16 bf16x8 __attribute__((ext_vector_type(8)));
typedef float  f32x4  __attribute__((ext_vector_type(4)));

__device__ __forceinline__ float bf2f(u16 v) {
    unsigned int u = ((unsigned int)v) << 16;
    return __uint_as_float(u);
}
__device__ __forceinline__ u16 f2bf(float f) {
    unsigned int u = __float_as_uint(f);
    u += 0x7fff + ((u >> 16) & 1);          // RTNE
    return (u16)(u >> 16);
}

__device__ __forceinline__ f32x4 mfma16(bf16x8 a, bf16x8 b, f32x4 c) {
    return __builtin_amdgcn_mfma_f32_16x16x32_bf16(a, b, c, 0, 0, 0);
}

// async global->LDS, 16 bytes per lane; LDS dst must be wave-uniform base + lane*16
__device__ __forceinline__ void gl_lds16(const u16* g, u16* l) {
    __builtin_amdgcn_global_load_lds(
        (const __attribute__((address_space(1))) unsigned int*)g,
        (__attribute__((address_space(3))) unsigned int*)l, 16, 0, 0);
}

// ---------------------------------------------------------------------------
// Weight prep (runs every launch; ~0.33M elems): build transposed bf16 weights
//  WvT[n][k] = Wv[k][n]; WoutT[n][k] = Wout[k][n];
//  WcT[80][384]: rows 0..47 = Wo cols, 48..71 = Wa cols, 72..79 = 0
//  bias_c[80]: bo | ba | 0
// ---------------------------------------------------------------------------
__global__ __launch_bounds__(256) void prep_weights(
    const float* __restrict__ Wv, const float* __restrict__ Wout,
    const float* __restrict__ Wo, const float* __restrict__ Wa,
    const float* __restrict__ bo, const float* __restrict__ ba,
    u16* __restrict__ WvT, u16* __restrict__ WoutT, u16* __restrict__ WcT,
    float* __restrict__ bias_c)
{
    const int KN = 384 * 384;
    int idx = blockIdx.x * 256 + threadIdx.x;
    if (idx < KN) {
        int n = idx / 384, k = idx - n * 384;
        WvT[idx] = f2bf(Wv[k * 384 + n]);
    } else if (idx < 2 * KN) {
        int t = idx - KN;
        int n = t / 384, k = t - n * 384;
        WoutT[t] = f2bf(Wout[k * 384 + n]);
    } else if (idx < 2 * KN + 80 * 384) {
        int t = idx - 2 * KN;
        int n = t / 384, k = t - n * 384;
        float v = (n < 48) ? Wo[k * 48 + n] : (n < 72 ? Wa[k * 24 + (n - 48)] : 0.f);
        WcT[t] = f2bf(v);
    } else if (idx < 2 * KN + 80 * 384 + 80) {
        int n = idx - (2 * KN + 80 * 384);
        bias_c[n] = (n < 48) ? bo[n] : (n < 72 ? ba[n - 48] : 0.f);
    }
}

// ---------------------------------------------------------------------------
// LayerNorm: one wave per row, bf16 output. Rows 0..16383 = query, rest = feat.
// ---------------------------------------------------------------------------
__global__ __launch_bounds__(256) void ln_kernel(
    const float* __restrict__ query, const float* __restrict__ feat,
    const float* __restrict__ qg, const float* __restrict__ qb,
    const float* __restrict__ fg, const float* __restrict__ fb,
    u16* __restrict__ qout, u16* __restrict__ fout)
{
    int wid  = threadIdx.x >> 6;
    int lane = threadIdx.x & 63;
    int row  = blockIdx.x * 4 + wid;          // 0 .. 32767
    const float *src, *g, *bsh;
    u16* dst;
    int r;
    if (row < ROWS_) { src = query; g = qg; bsh = qb; dst = qout; r = row; }
    else             { src = feat;  g = fg; bsh = fb; dst = fout; r = row - ROWS_; }

    const float* x = src + (size_t)r * C_;
    float v[6];
    float s = 0.f;
#pragma unroll
    for (int k = 0; k < 6; ++k) { v[k] = x[lane + 64 * k]; s += v[k]; }
#pragma unroll
    for (int off = 32; off; off >>= 1) s += __shfl_xor(s, off);
    float mu = s * (1.f / C_);

    float s2 = 0.f;
#pragma unroll
    for (int k = 0; k < 6; ++k) { float d = v[k] - mu; s2 += d * d; }
#pragma unroll
    for (int off = 32; off; off >>= 1) s2 += __shfl_xor(s2, off);
    float rs = rsqrtf(s2 * (1.f / C_) + EPS_);

    u16* y = dst + (size_t)r * C_;
#pragma unroll
    for (int k = 0; k < 6; ++k) {
        int c = lane + 64 * k;
        y[c] = f2bf((v[k] - mu) * rs * g[c] + bsh[c]);
    }
}

// ---------------------------------------------------------------------------
// BF16 MFMA GEMM, C[M,384] = A[M,384] @ B'[384,384]^T (B' is N-major [n][k]).
// 128x128 tile, 256 threads = 4 waves (2x2 of 64x64), BK=32, 16x16x32 MFMA.
// MODE 0: Cout(bf16) = acc + bias      (value GEMM)
// MODE 1: Cout(f32)  = resid + gamma*(acc + bias)   (output GEMM)
// ---------------------------------------------------------------------------
template<int MODE>
__global__ __launch_bounds__(256) void mfma_gemm(
    const u16* __restrict__ A, const u16* __restrict__ Bt,
    const float* __restrict__ bias, const float* __restrict__ resid,
    const float* __restrict__ gamma, void* __restrict__ Cout)
{
    const int K = 384, N = 384;
    __shared__ __align__(16) u16 As[128 * 32];
    __shared__ __align__(16) u16 Bs[128 * 32];

    int tid  = threadIdx.x;
    int lane = tid & 63, wid = tid >> 6;
    int m0 = blockIdx.y * 128, n0 = blockIdx.x * 128;
    int wm = (wid >> 1) * 64, wn = (wid & 1) * 64;
    int fr = lane & 15, quad = lane >> 4;

    int srow = tid >> 2;                  // 0..63
    int scol = (tid & 3) * 8;             // 0,8,16,24 elements
    const u16* agp0 = A  + (size_t)(m0 + srow) * K + scol;
    const u16* agp1 = A  + (size_t)(m0 + srow + 64) * K + scol;
    const u16* bgp0 = Bt + (size_t)(n0 + srow) * K + scol;
    const u16* bgp1 = Bt + (size_t)(n0 + srow + 64) * K + scol;
    u16* al0 = As + tid * 8;  u16* al1 = As + 2048 + tid * 8;
    u16* bl0 = Bs + tid * 8;  u16* bl1 = Bs + 2048 + tid * 8;

    f32x4 zero = {0.f, 0.f, 0.f, 0.f};
    f32x4 acc[4][4];
#pragma unroll
    for (int i = 0; i < 4; ++i)
#pragma unroll
        for (int j = 0; j < 4; ++j) acc[i][j] = zero;

    for (int k0 = 0; k0 < K; k0 += 32) {
        gl_lds16(agp0 + k0, al0);
        gl_lds16(agp1 + k0, al1);
        gl_lds16(bgp0 + k0, bl0);
        gl_lds16(bgp1 + k0, bl1);
        __syncthreads();                  // drains vmcnt before reads
        bf16x8 af[4], bfr[4];
#pragma unroll
        for (int i = 0; i < 4; ++i)
            af[i] = *(bf16x8*)&As[(wm + i * 16 + fr) * 32 + quad * 8];
#pragma unroll
        for (int j = 0; j < 4; ++j)
            bfr[j] = *(bf16x8*)&Bs[(wn + j * 16 + fr) * 32 + quad * 8];
#pragma unroll
        for (int i = 0; i < 4; ++i)
#pragma unroll
            for (int j = 0; j < 4; ++j)
                acc[i][j] = mfma16(af[i], bfr[j], acc[i][j]);
        __syncthreads();                  // protect LDS before next staging
    }

#pragma unroll
    for (int i = 0; i < 4; ++i) {
        int row = m0 + wm + i * 16 + quad * 4;
#pragma unroll
        for (int j = 0; j < 4; ++j) {
            int col = n0 + wn + j * 16 + fr;
            float bcol = bias[col];
#pragma unroll
            for (int r = 0; r < 4; ++r) {
                float v = acc[i][j][r] + bcol;
                size_t o = (size_t)(row + r) * N + col;
                if (MODE == 0) ((u16*)Cout)[o] = f2bf(v);
                else ((float*)Cout)[o] = resid[o] + gamma[col] * v;
            }
        }
    }
}

// ---------------------------------------------------------------------------
// Small MFMA GEMM: [16384 x 384] @ [384 x 80] (WcT is [80][384] n-major).
// Whole B' resident in LDS (60 KB); 64-row M tile per block, 4 waves.
// cols 0..47 -> offs, 48..71 -> logits, 72..79 dropped.
// ---------------------------------------------------------------------------
__global__ __launch_bounds__(256) void mfma_small(
    const u16* __restrict__ A, const u16* __restrict__ Bt,
    const float* __restrict__ bias,
    float* __restrict__ offs, float* __restrict__ logits)
{
    const int K = 384;
    __shared__ __align__(16) u16 Bs[80 * 384];   // 61440 B
    __shared__ __align__(16) u16 As[64 * 32];    //  4096 B

    int tid  = threadIdx.x;
    int lane = tid & 63, wid = tid >> 6;
    int m0 = blockIdx.x * 64;
    int fr = lane & 15, quad = lane >> 4;

    // preload whole B' (3840 x 16B)
    for (int i = tid; i < 3840; i += 256)
        ((float4*)Bs)[i] = ((const float4*)Bt)[i];

    int srow = tid >> 2, scol = (tid & 3) * 8;
    const u16* agp = A + (size_t)(m0 + srow) * K + scol;
    u16* al = As + tid * 8;

    f32x4 zero = {0.f, 0.f, 0.f, 0.f};
    f32x4 acc[5];
#pragma unroll
    for (int j = 0; j < 5; ++j) acc[j] = zero;

    __syncthreads();                       // Bs visible

    for (int k0 = 0; k0 < K; k0 += 32) {
        gl_lds16(agp + k0, al);
        __syncthreads();
        bf16x8 af = *(bf16x8*)&As[(wid * 16 + fr) * 32 + quad * 8];
#pragma unroll
        for (int j = 0; j < 5; ++j) {
            bf16x8 bf = *(bf16x8*)&Bs[(j * 16 + fr) * 384 + k0 + quad * 8];
            acc[j] = mfma16(af, bf, acc[j]);
        }
        __syncthreads();
    }

    int row = m0 + wid * 16 + quad * 4;
#pragma unroll
    for (int j = 0; j < 5; ++j) {
        int col = j * 16 + fr;
        if (col < 72) {
            float bcol = bias[col];
#pragma unroll
            for (int r = 0; r < 4; ++r) {
                float v = acc[j][r] + bcol;
                if (col < 48) offs[(size_t)(row + r) * NOFF_ + col] = v;
                else          logits[(size_t)(row + r) * NLOG_ + (col - 48)] = v;
            }
        }
    }
}

// ---------------------------------------------------------------------------
// Fused softmax(4) + bilinear sampling; value/attn in bf16.
// One block per (b,q), 384 threads = (h,d).
// ---------------------------------------------------------------------------
__global__ __launch_bounds__(384) void sample_kernel(
    const u16*  __restrict__ value,    // [B*LV, C] bf16
    const float* __restrict__ rp,      // [B*LQ, 2]
    const float* __restrict__ offs,    // [B*LQ, 48]
    const float* __restrict__ logits,  // [B*LQ, 24]
    u16* __restrict__ attn)            // [B*LQ, C] bf16
{
    __shared__ float w_s[NH_][NP_][4];
    __shared__ int   pos_s[NH_][NP_][4];

    int bq = blockIdx.x;
    int b  = bq / LQ_;
    int t  = threadIdx.x;

    if (t < NLOG_) {
        int h = t >> 2, p = t & 3;
        const float* lg = logits + (size_t)bq * NLOG_ + h * 4;
        float l0 = lg[0], l1 = lg[1], l2 = lg[2], l3 = lg[3];
        float mx = fmaxf(fmaxf(l0, l1), fmaxf(l2, l3));
        float e0 = expf(l0 - mx), e1 = expf(l1 - mx), e2 = expf(l2 - mx), e3 = expf(l3 - mx);
        float den = e0 + e1 + e2 + e3;
        float ep = (p == 0) ? e0 : (p == 1) ? e1 : (p == 2) ? e2 : e3;
        float aw = ep / den;

        float rx = rp[(size_t)bq * 2 + 0];
        float ry = rp[(size_t)bq * 2 + 1];
        float ox = offs[(size_t)bq * NOFF_ + t * 2 + 0];
        float oy = offs[(size_t)bq * NOFF_ + t * 2 + 1];
        float x = (rx + ox * (1.0f / WL_)) * (float)WL_ - 0.5f;
        float y = (ry + oy * (1.0f / HL_)) * (float)HL_ - 0.5f;
        float x0f = floorf(x), y0f = floorf(y);
        float wx = x - x0f, wy = y - y0f;
        int x0 = (int)x0f, y0 = (int)y0f;
#pragma unroll
        for (int c = 0; c < 4; ++c) {
            int xi = x0 + (c & 1);
            int yi = y0 + (c >> 1);
            bool valid = (xi >= 0) && (xi < WL_) && (yi >= 0) && (yi < HL_);
            int xc = xi < 0 ? 0 : (xi > WL_ - 1 ? WL_ - 1 : xi);
            int yc = yi < 0 ? 0 : (yi > HL_ - 1 ? HL_ - 1 : yi);
            float wc = ((c & 1) ? wx : 1.f - wx) * ((c >> 1) ? wy : 1.f - wy);
            pos_s[h][p][c] = yc * WL_ + xc;
            w_s[h][p][c]   = valid ? wc * aw : 0.f;
        }
    }
    __syncthreads();

    int h = t >> 6, d = t & 63;
    const u16* vb = value + ((size_t)b * LV_) * C_ + h * 64 + d;
    float acc = 0.f;
#pragma unroll
    for (int p = 0; p < NP_; ++p) {
#pragma unroll
        for (int c = 0; c < 4; ++c) {
            acc += w_s[h][p][c] * bf2f(vb[(size_t)pos_s[h][p][c] * C_]);
        }
    }
    attn[(size_t)bq * C_ + t] = f2bf(acc);
}

// ---------------------------------------------------------------------------
extern "C" void kernel_launch(void* const* d_in, const int* in_sizes, int n_in,
                              void* d_out, int out_size, void* d_ws, size_t ws_size,
                              hipStream_t stream)
{
    const float* query  = (const float*)d_in[0];
    const float* rp     = (const float*)d_in[1];
    const float* feat   = (const float*)d_in[2];
    const float* gamma  = (const float*)d_in[9];
    const float* Wv     = (const float*)d_in[10];
    const float* bv     = (const float*)d_in[11];
    const float* Wo     = (const float*)d_in[12];
    const float* bo     = (const float*)d_in[13];
    const float* Wa     = (const float*)d_in[14];
    const float* ba     = (const float*)d_in[15];
    const float* Wout   = (const float*)d_in[16];
    const float* bout   = (const float*)d_in[17];
    float* out = (float*)d_out;

    // Workspace layout
    u16* wsu    = (u16*)d_ws;
    u16* qb     = wsu;                                   // 16384*384
    u16* fb     = qb    + (size_t)ROWS_ * C_;
    u16* valb   = fb    + (size_t)ROWS_ * C_;
    u16* attnb  = valb  + (size_t)ROWS_ * C_;
    u16* WvT    = attnb + (size_t)ROWS_ * C_;            // 384*384
    u16* WoutT  = WvT   + 384 * 384;
    u16* WcT    = WoutT + 384 * 384;                     // 80*384
    float* offs   = (float*)(WcT + 80 * 384);            // 16384*48
    float* logits = offs + (size_t)ROWS_ * NOFF_;        // 16384*24
    float* bias_c = logits + (size_t)ROWS_ * NLOG_;      // 80
    // total ~55.7 MB

    // 1) transpose+convert weights to bf16
    prep_weights<<<1273, 256, 0, stream>>>(Wv, Wout, Wo, Wa, bo, ba,
                                           WvT, WoutT, WcT, bias_c);

    // 2) LayerNorm query & feat -> bf16
    ln_kernel<<<8192, 256, 0, stream>>>(query, feat,
        (const float*)d_in[5], (const float*)d_in[6],
        (const float*)d_in[7], (const float*)d_in[8], qb, fb);

    // 3) value = ln(feat) @ Wv + bv   (bf16 out)
    mfma_gemm<0><<<dim3(3, 128), 256, 0, stream>>>(fb, WvT, bv, nullptr, nullptr, valb);

    // 4) offs/logits = ln(q) @ [Wo|Wa] + [bo|ba]
    mfma_small<<<256, 256, 0, stream>>>(qb, WcT, bias_c, offs, logits);

    // 5) softmax + bilinear sampling -> attn (bf16)
    sample_kernel<<<ROWS_, 384, 0, stream>>>(valb, rp, offs, logits, attnb);

    // 6) out = query + gamma * (attn @ Wout + bout)
    mfma_gemm<1><<<dim3(3, 128), 256, 0, stream>>>(attnb, WoutT, bout, query, gamma, out);
}

// Round 3
// 190.584 us; speedup vs baseline: 2.3705x; 1.0633x over previous
//
#include <hip/hip_runtime.h>
#include <math.h>

// Problem constants (fixed by the reference file)
#define B_    4
#define LQ_   4096
#define C_    384
#define NH_   6
#define NP_   4
#define HL_   64
#define WL_   64
#define LV_   (HL_ * WL_)          // 4096
#define ROWS_ (B_ * LQ_)           // 16384
#define EPS_  1e-6f
#define NOFF_ 48                   // NH*NL*NP*2
#define NLOG_ 24                   // NH*NL*NP

typedef unsigned short u16;
typedef __bf16 bf16x8 __attribute__((ext_vector_type(8)));
typedef float  f32x4  __attribute__((ext_vector_type(4)));

__device__ __forceinline__ float bf2f(u16 v) {
    unsigned int u = ((unsigned int)v) << 16;
    return __uint_as_float(u);
}
__device__ __forceinline__ u16 f2bf(float f) {
    unsigned int u = __float_as_uint(f);
    u += 0x7fff + ((u >> 16) & 1);          // RTNE
    return (u16)(u >> 16);
}

__device__ __forceinline__ f32x4 mfma16(bf16x8 a, bf16x8 b, f32x4 c) {
    return __builtin_amdgcn_mfma_f32_16x16x32_bf16(a, b, c, 0, 0, 0);
}

// async global->LDS, 16 bytes per lane; LDS dst must be wave-uniform base + lane*16
__device__ __forceinline__ void gl_lds16(const u16* g, u16* l) {
    __builtin_amdgcn_global_load_lds(
        (const __attribute__((address_space(1))) unsigned int*)g,
        (__attribute__((address_space(3))) unsigned int*)l, 16, 0, 0);
}

// ---------------------------------------------------------------------------
// Weight prep: WvT[n][k]=Wv[k][n]; WoutT[n][k]=Wout[k][n];
// WcT[80][384]: rows 0..47 = Wo cols, 48..71 = Wa cols, 72..79 = 0; bias_c[80].
// ---------------------------------------------------------------------------
__global__ __launch_bounds__(256) void prep_weights(
    const float* __restrict__ Wv, const float* __restrict__ Wout,
    const float* __restrict__ Wo, const float* __restrict__ Wa,
    const float* __restrict__ bo, const float* __restrict__ ba,
    u16* __restrict__ WvT, u16* __restrict__ WoutT, u16* __restrict__ WcT,
    float* __restrict__ bias_c)
{
    const int KN = 384 * 384;
    int idx = blockIdx.x * 256 + threadIdx.x;
    if (idx < KN) {
        int n = idx / 384, k = idx - n * 384;
        WvT[idx] = f2bf(Wv[k * 384 + n]);
    } else if (idx < 2 * KN) {
        int t = idx - KN;
        int n = t / 384, k = t - n * 384;
        WoutT[t] = f2bf(Wout[k * 384 + n]);
    } else if (idx < 2 * KN + 80 * 384) {
        int t = idx - 2 * KN;
        int n = t / 384, k = t - n * 384;
        float v = (n < 48) ? Wo[k * 48 + n] : (n < 72 ? Wa[k * 24 + (n - 48)] : 0.f);
        WcT[t] = f2bf(v);
    } else if (idx < 2 * KN + 80 * 384 + 80) {
        int n = idx - (2 * KN + 80 * 384);
        bias_c[n] = (n < 48) ? bo[n] : (n < 72 ? ba[n - 48] : 0.f);
    }
}

// ---------------------------------------------------------------------------
// LayerNorm: one wave per row, bf16 output. Rows 0..16383 = query, rest = feat.
// ---------------------------------------------------------------------------
__global__ __launch_bounds__(256) void ln_kernel(
    const float* __restrict__ query, const float* __restrict__ feat,
    const float* __restrict__ qg, const float* __restrict__ qb,
    const float* __restrict__ fg, const float* __restrict__ fb,
    u16* __restrict__ qout, u16* __restrict__ fout)
{
    int wid  = threadIdx.x >> 6;
    int lane = threadIdx.x & 63;
    int row  = blockIdx.x * 4 + wid;          // 0 .. 32767
    const float *src, *g, *bsh;
    u16* dst;
    int r;
    if (row < ROWS_) { src = query; g = qg; bsh = qb; dst = qout; r = row; }
    else             { src = feat;  g = fg; bsh = fb; dst = fout; r = row - ROWS_; }

    const float* x = src + (size_t)r * C_;
    float v[6];
    float s = 0.f;
#pragma unroll
    for (int k = 0; k < 6; ++k) { v[k] = x[lane + 64 * k]; s += v[k]; }
#pragma unroll
    for (int off = 32; off; off >>= 1) s += __shfl_xor(s, off);
    float mu = s * (1.f / C_);

    float s2 = 0.f;
#pragma unroll
    for (int k = 0; k < 6; ++k) { float d = v[k] - mu; s2 += d * d; }
#pragma unroll
    for (int off = 32; off; off >>= 1) s2 += __shfl_xor(s2, off);
    float rs = rsqrtf(s2 * (1.f / C_) + EPS_);

    u16* y = dst + (size_t)r * C_;
#pragma unroll
    for (int k = 0; k < 6; ++k) {
        int c = lane + 64 * k;
        y[c] = f2bf((v[k] - mu) * rs * g[c] + bsh[c]);
    }
}

// ---------------------------------------------------------------------------
// BF16 MFMA GEMM (value): C[M,384](bf16) = A[M,384] @ Bt[384,384]^T + bias.
// 128x128 tile, 256 threads = 4 waves (2x2 of 64x64), BK=32, 16x16x32 MFMA.
// ---------------------------------------------------------------------------
__global__ __launch_bounds__(256) void mfma_gemm_value(
    const u16* __restrict__ A, const u16* __restrict__ Bt,
    const float* __restrict__ bias, u16* __restrict__ Cout)
{
    const int K = 384, N = 384;
    __shared__ __align__(16) u16 As[128 * 32];
    __shared__ __align__(16) u16 Bs[128 * 32];

    int tid  = threadIdx.x;
    int lane = tid & 63, wid = tid >> 6;
    int m0 = blockIdx.y * 128, n0 = blockIdx.x * 128;
    int wm = (wid >> 1) * 64, wn = (wid & 1) * 64;
    int fr = lane & 15, quad = lane >> 4;

    int srow = tid >> 2;                  // 0..63
    int scol = (tid & 3) * 8;             // 0,8,16,24 elements
    const u16* agp0 = A  + (size_t)(m0 + srow) * K + scol;
    const u16* agp1 = A  + (size_t)(m0 + srow + 64) * K + scol;
    const u16* bgp0 = Bt + (size_t)(n0 + srow) * K + scol;
    const u16* bgp1 = Bt + (size_t)(n0 + srow + 64) * K + scol;
    u16* al0 = As + tid * 8;  u16* al1 = As + 2048 + tid * 8;
    u16* bl0 = Bs + tid * 8;  u16* bl1 = Bs + 2048 + tid * 8;

    f32x4 zero = {0.f, 0.f, 0.f, 0.f};
    f32x4 acc[4][4];
#pragma unroll
    for (int i = 0; i < 4; ++i)
#pragma unroll
        for (int j = 0; j < 4; ++j) acc[i][j] = zero;

    for (int k0 = 0; k0 < K; k0 += 32) {
        gl_lds16(agp0 + k0, al0);
        gl_lds16(agp1 + k0, al1);
        gl_lds16(bgp0 + k0, bl0);
        gl_lds16(bgp1 + k0, bl1);
        __syncthreads();
        bf16x8 af[4], bfr[4];
#pragma unroll
        for (int i = 0; i < 4; ++i)
            af[i] = *(bf16x8*)&As[(wm + i * 16 + fr) * 32 + quad * 8];
#pragma unroll
        for (int j = 0; j < 4; ++j)
            bfr[j] = *(bf16x8*)&Bs[(wn + j * 16 + fr) * 32 + quad * 8];
#pragma unroll
        for (int i = 0; i < 4; ++i)
#pragma unroll
            for (int j = 0; j < 4; ++j)
                acc[i][j] = mfma16(af[i], bfr[j], acc[i][j]);
        __syncthreads();
    }

#pragma unroll
    for (int i = 0; i < 4; ++i) {
        int row = m0 + wm + i * 16 + quad * 4;
#pragma unroll
        for (int j = 0; j < 4; ++j) {
            int col = n0 + wn + j * 16 + fr;
            float bcol = bias[col];
#pragma unroll
            for (int r = 0; r < 4; ++r) {
                float v = acc[i][j][r] + bcol;
                Cout[(size_t)(row + r) * N + col] = f2bf(v);
            }
        }
    }
}

// ---------------------------------------------------------------------------
// Small MFMA GEMM: [16384 x 384] @ [384 x 80]; whole B' in LDS.
// cols 0..47 -> offs, 48..71 -> logits.
// ---------------------------------------------------------------------------
__global__ __launch_bounds__(256) void mfma_small(
    const u16* __restrict__ A, const u16* __restrict__ Bt,
    const float* __restrict__ bias,
    float* __restrict__ offs, float* __restrict__ logits)
{
    const int K = 384;
    __shared__ __align__(16) u16 Bs[80 * 384];   // 61440 B
    __shared__ __align__(16) u16 As[64 * 32];    //  4096 B

    int tid  = threadIdx.x;
    int lane = tid & 63, wid = tid >> 6;
    int m0 = blockIdx.x * 64;
    int fr = lane & 15, quad = lane >> 4;

    for (int i = tid; i < 3840; i += 256)
        ((float4*)Bs)[i] = ((const float4*)Bt)[i];

    int srow = tid >> 2, scol = (tid & 3) * 8;
    const u16* agp = A + (size_t)(m0 + srow) * K + scol;
    u16* al = As + tid * 8;

    f32x4 zero = {0.f, 0.f, 0.f, 0.f};
    f32x4 acc[5];
#pragma unroll
    for (int j = 0; j < 5; ++j) acc[j] = zero;

    __syncthreads();

    for (int k0 = 0; k0 < K; k0 += 32) {
        gl_lds16(agp + k0, al);
        __syncthreads();
        bf16x8 af = *(bf16x8*)&As[(wid * 16 + fr) * 32 + quad * 8];
#pragma unroll
        for (int j = 0; j < 5; ++j) {
            bf16x8 bf = *(bf16x8*)&Bs[(j * 16 + fr) * 384 + k0 + quad * 8];
            acc[j] = mfma16(af, bf, acc[j]);
        }
        __syncthreads();
    }

    int row = m0 + wid * 16 + quad * 4;
#pragma unroll
    for (int j = 0; j < 5; ++j) {
        int col = j * 16 + fr;
        if (col < 72) {
            float bcol = bias[col];
#pragma unroll
            for (int r = 0; r < 4; ++r) {
                float v = acc[j][r] + bcol;
                if (col < 48) offs[(size_t)(row + r) * NOFF_ + col] = v;
                else          logits[(size_t)(row + r) * NLOG_ + (col - 48)] = v;
            }
        }
    }
}

// ---------------------------------------------------------------------------
// Fused: softmax + bilinear sampling (vectorized bf16x8 gathers) -> LDS attn
// tile -> MFMA with WoutT (L2-resident, read direct from global) -> residual
// epilogue. One block = 32 queries, 256 threads = 4 waves.
// ---------------------------------------------------------------------------
#define QT_   32                     // queries per block
#define APAD_ 392                    // attn tile row stride in u16 (384 + 8)

__global__ __launch_bounds__(256) void fused_sample_out(
    const u16*  __restrict__ value,    // [B*LV, 384] bf16
    const float* __restrict__ rp,      // [B*LQ, 2]
    const float* __restrict__ offs,    // [B*LQ, 48]
    const float* __restrict__ logits,  // [B*LQ, 24]
    const u16*  __restrict__ WoutT,    // [384][384] n-major bf16
    const float* __restrict__ bout,
    const float* __restrict__ gamma,
    const float* __restrict__ query,   // residual
    float* __restrict__ out)
{
    __shared__ float meta[QT_ * NH_ * NP_ * 4];      // wx, wy, aw, packed(x0,y0)
    __shared__ __align__(16) u16 attn_s[QT_ * APAD_];

    int t  = threadIdx.x;
    int m0 = blockIdx.x * QT_;
    int b  = m0 / LQ_;                 // 32 | 4096 so uniform per block

    // ---- phase 1: per-(q,h,p) softmax weight + sample coords ----
#pragma unroll
    for (int j = 0; j < 3; ++j) {
        int u = t + 256 * j;           // 0 .. 767
        int q = u / (NH_ * NP_);
        int rem = u - q * (NH_ * NP_);
        int h = rem >> 2, p = rem & 3;
        int r = m0 + q;

        const float* lg = logits + (size_t)r * NLOG_ + h * 4;
        float l0 = lg[0], l1 = lg[1], l2 = lg[2], l3 = lg[3];
        float mx = fmaxf(fmaxf(l0, l1), fmaxf(l2, l3));
        float e0 = expf(l0 - mx), e1 = expf(l1 - mx);
        float e2 = expf(l2 - mx), e3 = expf(l3 - mx);
        float den = e0 + e1 + e2 + e3;
        float ep = (p == 0) ? e0 : (p == 1) ? e1 : (p == 2) ? e2 : e3;
        float aw = ep / den;

        float rx = rp[(size_t)r * 2 + 0];
        float ry = rp[(size_t)r * 2 + 1];
        float ox = offs[(size_t)r * NOFF_ + (h * 4 + p) * 2 + 0];
        float oy = offs[(size_t)r * NOFF_ + (h * 4 + p) * 2 + 1];
        float x = rx * (float)WL_ + ox - 0.5f;
        float y = ry * (float)HL_ + oy - 0.5f;
        float x0f = floorf(x), y0f = floorf(y);
        int x0 = (int)x0f, y0 = (int)y0f;

        int midx = u * 4;
        meta[midx + 0] = x - x0f;                       // wx
        meta[midx + 1] = y - y0f;                       // wy
        meta[midx + 2] = aw;
        meta[midx + 3] = __int_as_float((y0 << 16) | (x0 & 0xffff));
    }
    __syncthreads();

    // ---- phase 2: vectorized gathers -> attn tile in LDS ----
#pragma unroll
    for (int j = 0; j < 6; ++j) {
        int v = t + 256 * j;           // 0 .. 1535
        int q = v / 48, dc = v - q * 48;
        int h = dc >> 3;
        int col0 = dc << 3;            // 0,8,...,376
        const u16* vbase = value + (size_t)b * LV_ * C_ + col0;

        float acc[8] = {0.f, 0.f, 0.f, 0.f, 0.f, 0.f, 0.f, 0.f};
#pragma unroll
        for (int p = 0; p < NP_; ++p) {
            int midx = ((q * NH_ + h) * NP_ + p) * 4;
            float wx = meta[midx + 0];
            float wy = meta[midx + 1];
            float aw = meta[midx + 2];
            int packed = __float_as_int(meta[midx + 3]);
            int x0 = (packed << 16) >> 16;
            int y0 = packed >> 16;
#pragma unroll
            for (int c = 0; c < 4; ++c) {
                int xi = x0 + (c & 1);
                int yi = y0 + (c >> 1);
                bool valid = (xi >= 0) && (xi < WL_) && (yi >= 0) && (yi < HL_);
                int xc = xi < 0 ? 0 : (xi > WL_ - 1 ? WL_ - 1 : xi);
                int yc = yi < 0 ? 0 : (yi > HL_ - 1 ? HL_ - 1 : yi);
                float w = ((c & 1) ? wx : 1.f - wx) * ((c >> 1) ? wy : 1.f - wy) * aw;
                w = valid ? w : 0.f;
                bf16x8 vv = *(const bf16x8*)(vbase + (size_t)(yc * WL_ + xc) * C_);
#pragma unroll
                for (int e = 0; e < 8; ++e) acc[e] += w * (float)vv[e];
            }
        }
        u16* dst = attn_s + q * APAD_ + col0;
#pragma unroll
        for (int e = 0; e < 8; ++e) dst[e] = f2bf(acc[e]);
    }
    __syncthreads();

    // ---- phase 3: attn(LDS) @ WoutT(global/L2) + residual epilogue ----
    int lane = t & 63, wid = t >> 6;
    int fr = lane & 15, quad = lane >> 4;
    int wn0 = wid * 96;                // each wave: 6 n-tiles of 16

    f32x4 zero = {0.f, 0.f, 0.f, 0.f};
    f32x4 acc[2][6];
#pragma unroll
    for (int i = 0; i < 2; ++i)
#pragma unroll
        for (int j = 0; j < 6; ++j) acc[i][j] = zero;

    for (int k0 = 0; k0 < 384; k0 += 32) {
        bf16x8 a0 = *(bf16x8*)&attn_s[(fr)      * APAD_ + k0 + quad * 8];
        bf16x8 a1 = *(bf16x8*)&attn_s[(16 + fr) * APAD_ + k0 + quad * 8];
#pragma unroll
        for (int nt = 0; nt < 6; ++nt) {
            bf16x8 bb = *(const bf16x8*)(WoutT + (size_t)(wn0 + nt * 16 + fr) * 384 + k0 + quad * 8);
            acc[0][nt] = mfma16(a0, bb, acc[0][nt]);
            acc[1][nt] = mfma16(a1, bb, acc[1][nt]);
        }
    }

#pragma unroll
    for (int nt = 0; nt < 6; ++nt) {
        int col = wn0 + nt * 16 + fr;
        float g = gamma[col], bc = bout[col];
#pragma unroll
        for (int mt = 0; mt < 2; ++mt) {
            int r0 = m0 + mt * 16 + quad * 4;
#pragma unroll
            for (int rr = 0; rr < 4; ++rr) {
                size_t o = (size_t)(r0 + rr) * C_ + col;
                out[o] = query[o] + g * (acc[mt][nt][rr] + bc);
            }
        }
    }
}

// ---------------------------------------------------------------------------
extern "C" void kernel_launch(void* const* d_in, const int* in_sizes, int n_in,
                              void* d_out, int out_size, void* d_ws, size_t ws_size,
                              hipStream_t stream)
{
    const float* query  = (const float*)d_in[0];
    const float* rp     = (const float*)d_in[1];
    const float* feat   = (const float*)d_in[2];
    const float* gamma  = (const float*)d_in[9];
    const float* Wv     = (const float*)d_in[10];
    const float* bv     = (const float*)d_in[11];
    const float* Wo     = (const float*)d_in[12];
    const float* bo     = (const float*)d_in[13];
    const float* Wa     = (const float*)d_in[14];
    const float* ba     = (const float*)d_in[15];
    const float* Wout   = (const float*)d_in[16];
    const float* bout   = (const float*)d_in[17];
    float* out = (float*)d_out;

    // Workspace layout
    u16* wsu    = (u16*)d_ws;
    u16* qb     = wsu;                                   // 16384*384
    u16* fb     = qb    + (size_t)ROWS_ * C_;
    u16* valb   = fb    + (size_t)ROWS_ * C_;
    u16* WvT    = valb  + (size_t)ROWS_ * C_;            // 384*384
    u16* WoutT  = WvT   + 384 * 384;
    u16* WcT    = WoutT + 384 * 384;                     // 80*384
    float* offs   = (float*)(WcT + 80 * 384);            // 16384*48
    float* logits = offs + (size_t)ROWS_ * NOFF_;        // 16384*24
    float* bias_c = logits + (size_t)ROWS_ * NLOG_;      // 80

    // 1) transpose+convert weights to bf16
    prep_weights<<<1273, 256, 0, stream>>>(Wv, Wout, Wo, Wa, bo, ba,
                                           WvT, WoutT, WcT, bias_c);

    // 2) LayerNorm query & feat -> bf16
    ln_kernel<<<8192, 256, 0, stream>>>(query, feat,
        (const float*)d_in[5], (const float*)d_in[6],
        (const float*)d_in[7], (const float*)d_in[8], qb, fb);

    // 3) value = ln(feat) @ Wv + bv   (bf16 out)
    mfma_gemm_value<<<dim3(3, 128), 256, 0, stream>>>(fb, WvT, bv, valb);

    // 4) offs/logits = ln(q) @ [Wo|Wa] + [bo|ba]
    mfma_small<<<256, 256, 0, stream>>>(qb, WcT, bias_c, offs, logits);

    // 5) fused: softmax + vectorized sampling + attn@Wout + residual
    fused_sample_out<<<ROWS_ / QT_, 256, 0, stream>>>(
        valb, rp, offs, logits, WoutT, bout, gamma, query, out);
}